// Round 1
// 378.024 us; speedup vs baseline: 1.0459x; 1.0459x over previous
//
#include <hip/hip_runtime.h>
#include <cstdint>
#include <cstddef>

#define B_ 4
#define M_ 4096
#define N_ 4096
#define F_ 8
#define H_ 128
#define O_ 8

// round-to-nearest-even float -> bf16 (as uint16 in low bits)
__device__ __forceinline__ uint32_t f2bf1(float x) {
    uint32_t u = __float_as_uint(x);
    return (u + 0x7fffu + ((u >> 16) & 1u)) >> 16;
}

// decode 8 packed bf16 (uint4) -> 8 floats; f[0] is low half of w.x
__device__ __forceinline__ void bf8dec(uint4 w, float* f) {
    f[0] = __uint_as_float(w.x << 16);
    f[1] = __uint_as_float(w.x & 0xffff0000u);
    f[2] = __uint_as_float(w.y << 16);
    f[3] = __uint_as_float(w.y & 0xffff0000u);
    f[4] = __uint_as_float(w.z << 16);
    f[5] = __uint_as_float(w.z & 0xffff0000u);
    f[6] = __uint_as_float(w.w << 16);
    f[7] = __uint_as_float(w.w & 0xffff0000u);
}

__device__ __forceinline__ float elu(float x) {
    return x > 0.f ? x : (__expf(x) - 1.f);
}

// nontemporal float4 load (adj is stream-once; keep it out of L2/L3)
typedef float vf4_t __attribute__((ext_vector_type(4)));
__device__ __forceinline__ float4 ntload4(const float4* p) {
    vf4_t v = __builtin_nontemporal_load((const vf4_t*)p);
    float4 r;
    r.x = v.x; r.y = v.y; r.z = v.z; r.w = v.w;
    return r;
}

// ---------------------------------------------------------------------------
// Fused kernel: per block (one batch, 32 rows of adj), 512 threads = 8 waves:
//   Phase A: b[32][8] = adj[rows] @ feat   (feat staged bf16 in 64 KB LDS,
//            fp32 accumulate, depth-1 prefetch of adj, butterfly reduce ->
//            every lane of wave wv holds all 4 of its rows' b-values)
//   Phase B: alias the (now dead) feat LDS with the MLP weights and run the
//            3-layer MLP on the wave-private rows; write c directly to out.
// grid = B*128 = 512 blocks, 2 blocks/CU -> 16 waves/CU (4/SIMD).
// ---------------------------------------------------------------------------
__global__ __launch_bounds__(512, 4)
void k_fused(const float* __restrict__ adj, const float* __restrict__ feat,
             const float* __restrict__ W1, const float* __restrict__ b1,
             const float* __restrict__ W2, const float* __restrict__ b2,
             const float* __restrict__ W3, const float* __restrict__ b3,
             float* __restrict__ out) {
    __shared__ alignas(16) unsigned char smem[65536];
    // phase A view
    uint4* sfeat = (uint4*)smem;  // 4096 * 16B = 64 KB
    // phase B view (all 16B-aligned offsets)
    float* sW1 = (float*)smem;                          // [128*8]    4096 B
    float* sW3 = (float*)(smem + 4096);                 // [8*132]    4224 B
    float* sB1 = (float*)(smem + 8320);                 // [128]       512 B
    float* sB2 = (float*)(smem + 8832);                 // [128]       512 B
    float* sB3 = (float*)(smem + 9344);                 // [8]          32 B
    float* sH  = (float*)(smem + 9376);                 // [32*132]  16896 B
    unsigned short* sW2b = (unsigned short*)(smem + 26272); // [128*136] bf16, 34816 B
    // total phase-B footprint 61088 B < 65536

    const int tid = threadIdx.x;
    const int bb  = blockIdx.x >> 7;   // batch
    const int rb  = blockIdx.x & 127;  // row-block (32 rows)

    // ---- stage feat[bb] -> bf16 LDS (4-plane layout: plane k = n%4==k) ----
    const float4* fsrc = (const float4*)(feat + (size_t)bb * (N_ * F_));
    for (int n = tid; n < N_; n += 512) {
        float4 lo = fsrc[2 * n];
        float4 hi = fsrc[2 * n + 1];
        uint4 w;
        w.x = f2bf1(lo.x) | (f2bf1(lo.y) << 16);
        w.y = f2bf1(lo.z) | (f2bf1(lo.w) << 16);
        w.z = f2bf1(hi.x) | (f2bf1(hi.y) << 16);
        w.w = f2bf1(hi.z) | (f2bf1(hi.w) << 16);
        sfeat[(n & 3) * 1024 + (n >> 2)] = w;
    }
    __syncthreads();

    const int lane = tid & 63;
    const int wv   = tid >> 6;          // 0..7
    const int m0   = rb * 32 + wv * 4;  // this wave's 4 rows

    const float4* arow = (const float4*)(adj + (size_t)(bb * M_ + m0) * N_);

    float acc[4][8];
#pragma unroll
    for (int r = 0; r < 4; ++r)
#pragma unroll
        for (int f = 0; f < 8; ++f) acc[r][f] = 0.f;

    // depth-1 prefetch: iter c's adj loads issue under iter c-1's compute
    float4 na0 = ntload4(arow + lane);
    float4 na1 = ntload4(arow + lane + 1024);
    float4 na2 = ntload4(arow + lane + 2048);
    float4 na3 = ntload4(arow + lane + 3072);

#pragma unroll 1
    for (int c = 0; c < 16; ++c) {
        const int ni = (c << 6) + lane;  // float4 index within the row
        float4 a0 = na0, a1 = na1, a2 = na2, a3 = na3;
        uint4 w0 = sfeat[ni];
        uint4 w1 = sfeat[1024 + ni];
        uint4 w2 = sfeat[2048 + ni];
        uint4 w3 = sfeat[3072 + ni];
        if (c < 15) {
            const int nn = ni + 64;
            na0 = ntload4(arow + nn);
            na1 = ntload4(arow + nn + 1024);
            na2 = ntload4(arow + nn + 2048);
            na3 = ntload4(arow + nn + 3072);
        }

        float av[4][4] = {{a0.x, a1.x, a2.x, a3.x},
                          {a0.y, a1.y, a2.y, a3.y},
                          {a0.z, a1.z, a2.z, a3.z},
                          {a0.w, a1.w, a2.w, a3.w}};
        uint4 ww[4] = {w0, w1, w2, w3};
#pragma unroll
        for (int k = 0; k < 4; ++k) {
            float f[8];
            bf8dec(ww[k], f);
#pragma unroll
            for (int r = 0; r < 4; ++r) {
                const float a = av[k][r];
#pragma unroll
                for (int j = 0; j < 8; ++j)
                    acc[r][j] = fmaf(a, f[j], acc[r][j]);
            }
        }
    }

    // ---- 64-lane butterfly: every lane ends with the full sums for its
    //      wave's 4 rows x 8 features ----
#pragma unroll
    for (int r = 0; r < 4; ++r)
#pragma unroll
        for (int j = 0; j < 8; ++j) {
            float v = acc[r][j];
            v += __shfl_xor(v, 32, 64);
            v += __shfl_xor(v, 16, 64);
            v += __shfl_xor(v, 8, 64);
            v += __shfl_xor(v, 4, 64);
            v += __shfl_xor(v, 2, 64);
            v += __shfl_xor(v, 1, 64);
            acc[r][j] = v;
        }

    __syncthreads();  // sfeat dead -> safe to overwrite with weights

    // ---- stage MLP weights into the aliased LDS ----
    for (int i = tid; i < H_ * F_ / 4; i += 512)  // tid<256 only
        ((float4*)sW1)[i] = ((const float4*)W1)[i];

    for (int i8 = tid; i8 < H_ * H_ / 8; i8 += 512) {  // 4 iters
        const int idx = i8 * 8;
        const int o = idx >> 7, k = idx & 127;
        float4 lo = ((const float4*)W2)[i8 * 2];
        float4 hi = ((const float4*)W2)[i8 * 2 + 1];
        uint4 w;
        w.x = f2bf1(lo.x) | (f2bf1(lo.y) << 16);
        w.y = f2bf1(lo.z) | (f2bf1(lo.w) << 16);
        w.z = f2bf1(hi.x) | (f2bf1(hi.y) << 16);
        w.w = f2bf1(hi.z) | (f2bf1(hi.w) << 16);
        // row stride 136 shorts = 272 B = 17 x 16B units -> lane-varying b128
        // reads are bank-spread, no swizzle needed
        *((uint4*)&sW2b[o * 136 + k]) = w;
    }

    for (int i = tid; i < O_ * H_ / 4; i += 512) {  // tid<256 only
        const int idx = i * 4;
        const int o = idx >> 7, k = idx & 127;
        *((float4*)&sW3[o * 132 + k]) = ((const float4*)W3)[i];
    }
    if (tid < H_) { sB1[tid] = b1[tid]; sB2[tid] = b2[tid]; }
    if (tid < O_) sB3[tid] = b3[tid];
    __syncthreads();

    // ---- layer 1: h1 = elu(b @ W1^T + b1); lane covers o=lane, o=lane+64;
    //      b-values are already in registers (acc) ----
    float w1a[8], w1b[8];
    {
        float4 x0 = *(const float4*)&sW1[lane * 8];
        float4 x1 = *(const float4*)&sW1[lane * 8 + 4];
        float4 y0 = *(const float4*)&sW1[(lane + 64) * 8];
        float4 y1 = *(const float4*)&sW1[(lane + 64) * 8 + 4];
        w1a[0]=x0.x; w1a[1]=x0.y; w1a[2]=x0.z; w1a[3]=x0.w;
        w1a[4]=x1.x; w1a[5]=x1.y; w1a[6]=x1.z; w1a[7]=x1.w;
        w1b[0]=y0.x; w1b[1]=y0.y; w1b[2]=y0.z; w1b[3]=y0.w;
        w1b[4]=y1.x; w1b[5]=y1.y; w1b[6]=y1.z; w1b[7]=y1.w;
    }
    const float bias1a = sB1[lane], bias1b = sB1[lane + 64];
#pragma unroll
    for (int r = 0; r < 4; ++r) {
        float t0 = bias1a, t1 = bias1b;
#pragma unroll
        for (int j = 0; j < 8; ++j) {
            t0 = fmaf(acc[r][j], w1a[j], t0);
            t1 = fmaf(acc[r][j], w1b[j], t1);
        }
        // rows are wave-private: no cross-wave hazard, no barrier needed
        sH[(wv * 4 + r) * 132 + lane]      = elu(t0);
        sH[(wv * 4 + r) * 132 + lane + 64] = elu(t1);
    }

    // ---- layer 2: h2 = elu(h1 @ W2^T + b2) ----
    float a20[4], a21[4];
#pragma unroll
    for (int r = 0; r < 4; ++r) { a20[r] = 0.f; a21[r] = 0.f; }
#pragma unroll 1
    for (int oct = 0; oct < 16; ++oct) {
        uint4 wa = *(const uint4*)&sW2b[lane * 136 + (oct << 3)];
        uint4 wb = *(const uint4*)&sW2b[(lane + 64) * 136 + (oct << 3)];
        float A[8], Bv[8];
        bf8dec(wa, A);
        bf8dec(wb, Bv);
#pragma unroll
        for (int r = 0; r < 4; ++r) {
            // same address across the wave -> LDS broadcast, conflict-free
            const float* hp = &sH[(wv * 4 + r) * 132 + (oct << 3)];
            float4 h0 = *(const float4*)hp;
            float4 h1v = *(const float4*)(hp + 4);
            float hv[8] = {h0.x, h0.y, h0.z, h0.w, h1v.x, h1v.y, h1v.z, h1v.w};
#pragma unroll
            for (int j = 0; j < 8; ++j) {
                a20[r] = fmaf(hv[j], A[j], a20[r]);
                a21[r] = fmaf(hv[j], Bv[j], a21[r]);
            }
        }
    }
    const float bias2a = sB2[lane], bias2b = sB2[lane + 64];
#pragma unroll
    for (int r = 0; r < 4; ++r) {
        // all reads of h1 for this wave's rows completed above; overwrite in place
        sH[(wv * 4 + r) * 132 + lane]      = elu(a20[r] + bias2a);
        sH[(wv * 4 + r) * 132 + lane + 64] = elu(a21[r] + bias2b);
    }

    // ---- layer 3: c = h2 @ W3^T + b3; lanes 0..31: row=lane>>3, o=lane&7 ----
    if (lane < 32) {
        const int rr = lane >> 3;
        const int oo = lane & 7;
        const float* hp = &sH[(wv * 4 + rr) * 132];
        const float* wp = &sW3[oo * 132];
        float s = sB3[oo];
#pragma unroll
        for (int k = 0; k < 128; k += 4) {
            float4 h = *(const float4*)(hp + k);
            float4 g = *(const float4*)(wp + k);
            s = fmaf(h.x, g.x, fmaf(h.y, g.y, fmaf(h.z, g.z, fmaf(h.w, g.w, s))));
        }
        out[(size_t)(bb * M_ + m0 + rr) * 8 + oo] = s;  // coalesced 128 B/wave
    }
}

extern "C" void kernel_launch(void* const* d_in, const int* in_sizes, int n_in,
                              void* d_out, int out_size, void* d_ws, size_t ws_size,
                              hipStream_t stream) {
    const float* feat = (const float*)d_in[0];
    const float* adj  = (const float*)d_in[1];
    const float* W1   = (const float*)d_in[2];
    const float* b1   = (const float*)d_in[3];
    const float* W2   = (const float*)d_in[4];
    const float* b2   = (const float*)d_in[5];
    const float* W3   = (const float*)d_in[6];
    const float* b3   = (const float*)d_in[7];
    float* outp = (float*)d_out;

    k_fused<<<dim3(B_ * 128), dim3(512), 0, stream>>>(
        adj, feat, W1, b1, W2, b2, W3, b3, outp);
}